// Round 1
// baseline (493.002 us; speedup 1.0000x reference)
//
#include <hip/hip_runtime.h>
#include <stdint.h>

// ---------------- problem constants ----------------
#define BATCH 16
#define NCLS 80
#define NPOS 21824            // 16384+4096+1024+256+64
#define POOLN 3320            // 1000+1000+1000+256+64
#define MAXDET 100

__device__ const int d_lvl_off[5] = {0, 16384, 20480, 21504, 21760};
__device__ const int d_lvl_hw[5]  = {16384, 4096, 1024, 256, 64};

struct Ptrs { const float* p[20]; };

// ---------------- bitonic sort (ascending, u64 keys, in LDS) ----------------
__device__ __forceinline__ void bitonic_sort(unsigned long long* s, int N, int tid, int nt) {
  for (int k = 2; k <= N; k <<= 1) {
    for (int j = k >> 1; j > 0; j >>= 1) {
      __syncthreads();
      for (int i = tid; i < N; i += nt) {
        int p = i ^ j;
        if (p > i) {
          unsigned long long a = s[i], b = s[p];
          bool up = ((i & k) == 0);
          if ((a > b) == up) { s[i] = b; s[p] = a; }
        }
      }
    }
  }
  __syncthreads();
}

// ---------------- kernel 1: decode ----------------
// One thread per (b, level, hw). Writes 16B entry {score_bits, class, box_lo, box_hi}
// and, for levels 3/4 (no top-k), the sort key directly into the pool.
__global__ __launch_bounds__(256) void decode_kernel(Ptrs args, uint4* __restrict__ dec,
                                                     unsigned long long* __restrict__ pool) {
  int flat = blockIdx.x * 256 + threadIdx.x;
  if (flat >= BATCH * NPOS) return;
  int b = flat / NPOS;
  int r = flat - b * NPOS;
  int level, hw;
  if      (r < 16384) { level = 0; hw = r; }
  else if (r < 20480) { level = 1; hw = r - 16384; }
  else if (r < 21504) { level = 2; hw = r - 20480; }
  else if (r < 21760) { level = 3; hw = r - 21504; }
  else                { level = 4; hw = r - 21760; }

  const float* cls = args.p[level * 4 + 0];
  const float* reg = args.p[level * 4 + 1];
  const float* ctr = args.p[level * 4 + 2];
  const float* pos = args.p[level * 4 + 3];
  long base = (long)b * d_lvl_hw[level] + hw;

  // argmax over 80 logits (first occurrence), sigmoid is monotone
  const float4* c4 = (const float4*)(cls + base * NCLS);
  float m = -1e30f; int am = 0;
#pragma unroll
  for (int c = 0; c < NCLS / 4; ++c) {
    float4 v = c4[c];
    if (v.x > m) { m = v.x; am = 4 * c + 0; }
    if (v.y > m) { m = v.y; am = 4 * c + 1; }
    if (v.z > m) { m = v.z; am = 4 * c + 2; }
    if (v.w > m) { m = v.w; am = 4 * c + 3; }
  }

  float4 rg = *(const float4*)(reg + base * 4);
  float  ct = ctr[base];
  float  px = pos[base * 2 + 0], py = pos[base * 2 + 1];

  float e0 = expf(rg.x), e1 = expf(rg.y), e2 = expf(rg.z), e3 = expf(rg.w);
  int x1 = (int)(px - e0);   // C truncation == .astype(int32)
  int y1 = (int)(py - e1);
  int x2 = (int)(px + e2);
  int y2 = (int)(py + e3);
  x1 = max(x1, 0); y1 = max(y1, 0);
  x2 = min(x2, 1023); y2 = min(y2, 1023);

  float sigm = 1.0f / (1.0f + expf(-m));
  float sigc = 1.0f / (1.0f + expf(-ct));
  float score = sqrtf(sigm * sigc);

  uint4 e;
  e.x = __float_as_uint(score);
  e.y = (unsigned)am;
  e.z = (unsigned)(x1 & 0xFFFF) | ((unsigned)y1 << 16);
  e.w = (unsigned)(x2 & 0xFFFF) | ((unsigned)y2 << 16);
  dec[flat] = e;

  if (level >= 3) {
    int slot = (level == 3) ? (3000 + hw) : (3256 + hw);
    unsigned sb = __float_as_uint(score);
    pool[b * POOLN + slot] =
        ((unsigned long long)(~sb) << 32) | (unsigned)((level << 20) | hw);
  }
}

// ---------------- kernel 2: per-level chunk sorts + top-1000 select ----------------
// 6 tasks per image: t0..t3 = level-0 4096-chunks -> stage0; t4 = level1 (4096) -> pool;
// t5 = level2 (1024) -> pool.
__global__ __launch_bounds__(512) void sort_select_kernel(const uint4* __restrict__ dec,
                                                          unsigned long long* __restrict__ pool,
                                                          unsigned long long* __restrict__ stage0) {
  __shared__ unsigned long long s[4096];
  int img = blockIdx.x / 6, t = blockIdx.x % 6;
  int tid = threadIdx.x, nt = blockDim.x;

  int level, base_hw, count, N;
  unsigned long long* dst;
  if (t < 4)      { level = 0; base_hw = t * 4096; count = 4096; N = 4096; dst = stage0 + img * 4000 + t * 1000; }
  else if (t == 4){ level = 1; base_hw = 0;        count = 4096; N = 4096; dst = pool + img * POOLN + 1000; }
  else            { level = 2; base_hw = 0;        count = 1024; N = 1024; dst = pool + img * POOLN + 2000; }

  for (int i = tid; i < N; i += nt) {
    unsigned long long key = ~0ULL;
    if (i < count) {
      int hw = base_hw + i;
      uint4 e = dec[img * NPOS + d_lvl_off[level] + hw];
      unsigned sb = e.x;
      key = ((unsigned long long)(~sb) << 32) | (unsigned)((level << 20) | hw);
    }
    s[i] = key;
  }
  bitonic_sort(s, N, tid, nt);
  for (int i = tid; i < 1000; i += nt) dst[i] = s[i];
}

// ---------------- kernel 3: per-image level-0 merge + final pool sort ----------------
__global__ __launch_bounds__(512) void merge_final_kernel(unsigned long long* __restrict__ pool,
                                                          const unsigned long long* __restrict__ stage0) {
  __shared__ unsigned long long s[4096];
  int img = blockIdx.x;
  int tid = threadIdx.x, nt = blockDim.x;

  // phase 1: merge level-0's 4x1000 -> top 1000 (left in s[0..1000))
  for (int i = tid; i < 4096; i += nt)
    s[i] = (i < 4000) ? stage0[img * 4000 + i] : ~0ULL;
  bitonic_sort(s, 4096, tid, nt);

  // phase 2: append levels 1..4 from pool, pad, final sort
  for (int i = tid; i < 4096; i += nt) {
    if (i >= 1000) s[i] = (i < POOLN) ? pool[img * POOLN + i] : ~0ULL;
  }
  bitonic_sort(s, 4096, tid, nt);

  for (int i = tid; i < POOLN; i += nt) pool[img * POOLN + i] = s[i];
}

// ---------------- kernel 4: per-image greedy NMS + output ----------------
__global__ __launch_bounds__(64) void nms_kernel(const uint4* __restrict__ dec,
                                                 const unsigned long long* __restrict__ pool,
                                                 float* __restrict__ out) {
  __shared__ float          s_score[POOLN];
  __shared__ unsigned short s_cls[POOLN];
  __shared__ uint2          s_box[POOLN];
  int img = blockIdx.x;
  int lane = threadIdx.x;

  for (int r = lane; r < POOLN; r += 64) {
    unsigned long long key = pool[img * POOLN + r];
    unsigned low = (unsigned)key;
    int level = (low >> 20) & 7;
    int idx = low & 0xFFFFF;
    uint4 e = dec[img * NPOS + d_lvl_off[level] + idx];
    s_score[r] = __uint_as_float(e.x);
    s_cls[r]   = (unsigned short)e.y;
    s_box[r]   = make_uint2(e.z, e.w);
  }
  __syncthreads();

  float* out_s = out + img * MAXDET;
  float* out_c = out + BATCH * MAXDET + img * MAXDET;
  float* out_b = out + 2 * BATCH * MAXDET + img * MAXDET * 4;

  // kept boxes: slot s lives in lane (s & 63), reg (s >> 6)
  int kx1[2], ky1[2], kx2[2], ky2[2], kar[2];
  int k = 0;

  for (int i = 0; i < POOLN; ++i) {
    float sc = s_score[i];
    if (!(sc > 0.01f)) break;   // sorted desc: all remaining are invalid too
    uint2 bx = s_box[i];
    int x1 = bx.x & 0xFFFF, y1 = bx.x >> 16;
    int x2 = bx.y & 0xFFFF, y2 = bx.y >> 16;
    int area = (x2 - x1) * (y2 - y1);

    bool sup = false;
#pragma unroll
    for (int sidx = 0; sidx < 2; ++sidx) {
      int slot = (sidx << 6) | lane;
      if (slot < k) {
        int xx1 = max(x1, kx1[sidx]), yy1 = max(y1, ky1[sidx]);
        int xx2 = min(x2, kx2[sidx]), yy2 = min(y2, ky2[sidx]);
        int iw = max(xx2 - xx1, 0), ih = max(yy2 - yy1, 0);
        int inter = iw * ih;
        // all intermediates are exact small ints -> identical fp32 division to ref
        float iou = (float)inter / (float)(area + kar[sidx] - inter);
        sup = sup || (iou > 0.6f);
      }
    }
    if (!__any(sup)) {
      if ((k & 63) == lane) {
        int hi = k >> 6;
        kx1[hi] = x1; ky1[hi] = y1; kx2[hi] = x2; ky2[hi] = y2; kar[hi] = area;
      }
      if (lane == 0) {
        out_s[k] = sc;
        out_c[k] = (float)(int)s_cls[i];
        out_b[k * 4 + 0] = (float)x1;
        out_b[k * 4 + 1] = (float)y1;
        out_b[k * 4 + 2] = (float)x2;
        out_b[k * 4 + 3] = (float)y2;
      }
      ++k;
      if (k == MAXDET) break;
    }
  }

  for (int s = k + lane; s < MAXDET; s += 64) {
    out_s[s] = -1.0f;
    out_c[s] = -1.0f;
    out_b[s * 4 + 0] = -1.0f;
    out_b[s * 4 + 1] = -1.0f;
    out_b[s * 4 + 2] = -1.0f;
    out_b[s * 4 + 3] = -1.0f;
  }
}

// ---------------- launcher ----------------
extern "C" void kernel_launch(void* const* d_in, const int* in_sizes, int n_in,
                              void* d_out, int out_size, void* d_ws, size_t ws_size,
                              hipStream_t stream) {
  Ptrs args;
  for (int i = 0; i < 20; ++i) args.p[i] = (const float*)d_in[i];

  uint4* dec = (uint4*)d_ws;                                   // 16*21824*16 = 5,586,944 B
  unsigned long long* pool   = (unsigned long long*)((char*)d_ws + (size_t)BATCH * NPOS * 16);
  unsigned long long* stage0 = pool + (size_t)BATCH * POOLN;   // +424,960 B, then 512,000 B
  float* out = (float*)d_out;

  int total = BATCH * NPOS;
  decode_kernel<<<(total + 255) / 256, 256, 0, stream>>>(args, dec, pool);
  sort_select_kernel<<<BATCH * 6, 512, 0, stream>>>(dec, pool, stage0);
  merge_final_kernel<<<BATCH, 512, 0, stream>>>(pool, stage0);
  nms_kernel<<<BATCH, 64, 0, stream>>>(dec, pool, out);
}

// Round 4
// 394.781 us; speedup vs baseline: 1.2488x; 1.2488x over previous
//
#include <hip/hip_runtime.h>
#include <stdint.h>

// ---------------- problem constants ----------------
#define BATCH 16
#define NCLS 80
#define NPOS 21824            // 16384+4096+1024+256+64
#define POOLN 3320            // 1000+1000+1000+256+64
#define MAXDET 100

// superset segment capacities (estimated max superset sizes ~1600/1150/1024; 2.5x margin)
#define CAP0 4096
#define CAP1 2432
#define CAP2 1024             // level 2 has only 1024 anchors total
#define CAP34 320             // levels 3+4 exactly (deterministic slots)
#define SEG1 (CAP0)                    // 4096
#define SEG2 (CAP0 + CAP1)             // 6528
#define SEG3 (CAP0 + CAP1 + CAP2)      // 7552
#define CAPTOT (SEG3 + CAP34)          // 7872
#define RANK_BLOCKS 31                 // 31*256 = 7936 >= CAPTOT

__device__ const int d_lvl_off[5] = {0, 16384, 20480, 21504, 21760};
__device__ const int d_lvl_hw[5]  = {16384, 4096, 1024, 256, 64};

struct Ptrs { const float* p[20]; };

__device__ __forceinline__ void map_lvl(int r, int& level, int& hw) {
  if      (r < 16384) { level = 0; hw = r; }
  else if (r < 20480) { level = 1; hw = r - 16384; }
  else if (r < 21504) { level = 2; hw = r - 20480; }
  else if (r < 21760) { level = 3; hw = r - 21504; }
  else                { level = 4; hw = r - 21760; }
}

// key = (~score_bits)<<32 | (level<<20) | hw; ascending == (score desc, level asc, idx asc).
// Matches lax.top_k tie-break (low idx) + stable concat order. Unique per image (proven: R1 passed).

// ---------------- kernel 1: decode (bit-identical to R1, proven) ----------------
__global__ __launch_bounds__(256) void decode_kernel(Ptrs args, uint4* __restrict__ dec) {
  int flat = blockIdx.x * 256 + threadIdx.x;
  if (flat >= BATCH * NPOS) return;
  int b = flat / NPOS;
  int r = flat - b * NPOS;
  int level, hw;
  map_lvl(r, level, hw);

  const float* cls = args.p[level * 4 + 0];
  const float* reg = args.p[level * 4 + 1];
  const float* ctr = args.p[level * 4 + 2];
  const float* pos = args.p[level * 4 + 3];
  long base = (long)b * d_lvl_hw[level] + hw;

  const float4* c4 = (const float4*)(cls + base * NCLS);
  float m = -1e30f; int am = 0;
#pragma unroll
  for (int c = 0; c < NCLS / 4; ++c) {
    float4 v = c4[c];
    if (v.x > m) { m = v.x; am = 4 * c + 0; }
    if (v.y > m) { m = v.y; am = 4 * c + 1; }
    if (v.z > m) { m = v.z; am = 4 * c + 2; }
    if (v.w > m) { m = v.w; am = 4 * c + 3; }
  }

  float4 rg = *(const float4*)(reg + base * 4);
  float  ct = ctr[base];
  float  px = pos[base * 2 + 0], py = pos[base * 2 + 1];

  float e0 = expf(rg.x), e1 = expf(rg.y), e2 = expf(rg.z), e3 = expf(rg.w);
  int x1 = (int)(px - e0);   // C truncation == .astype(int32)
  int y1 = (int)(py - e1);
  int x2 = (int)(px + e2);
  int y2 = (int)(py + e3);
  x1 = max(x1, 0); y1 = max(y1, 0);
  x2 = min(x2, 1023); y2 = min(y2, 1023);

  float sigm = 1.0f / (1.0f + expf(-m));
  float sigc = 1.0f / (1.0f + expf(-ct));
  float score = sqrtf(sigm * sigc);

  uint4 e;
  e.x = __float_as_uint(score);
  e.y = (unsigned)am;
  e.z = (unsigned)(x1 & 0xFFFF) | ((unsigned)y1 << 16);
  e.w = (unsigned)(x2 & 0xFFFF) | ((unsigned)y2 << 16);
  dec[flat] = e;
}

// ---------------- kernel 2: per-(img,level) coarse digit cutoff ----------------
// digit = (~score_bits) >> 19 is a 13-bit PREFIX of the sort key, so {digit <= B}
// is downward-closed in key order. Pick smallest B with cum >= 1000.
__global__ __launch_bounds__(256) void hist_kernel(const uint4* __restrict__ dec,
                                                   int* __restrict__ bcut) {
  __shared__ unsigned hist[8192];
  __shared__ unsigned part[256];
  int img = blockIdx.x / 3, level = blockIdx.x % 3;
  int N = d_lvl_hw[level];
  const uint4* base = dec + img * NPOS + d_lvl_off[level];
  int tid = threadIdx.x;

  for (int i = tid; i < 8192; i += 256) hist[i] = 0;
  __syncthreads();
  for (int i = tid; i < N; i += 256)
    atomicAdd(&hist[(~base[i].x) >> 19], 1u);
  __syncthreads();
  unsigned s = 0;
  for (int b = 32 * tid; b < 32 * tid + 32; ++b) s += hist[b];
  part[tid] = s;
  __syncthreads();
  if (tid == 0) {
    unsigned cum = 0; int B = 8191;
    for (int t = 0; t < 256; ++t) {
      if (cum + part[t] >= 1000u) {
        for (int b = 32 * t; b < 32 * t + 32; ++b) {
          cum += hist[b];
          if (cum >= 1000u) { B = b; break; }
        }
        break;
      }
      cum += part[t];
    }
    bcut[img * 3 + level] = B;
  }
}

// ---------------- kernel 3a: SINGLE-instance gather of supersets -> global ----
// One block per image. The slot<->element mapping is created exactly once, so all
// rank blocks see the same layout (this fixes the R2/R3 coverage bug: per-block
// redundant atomic gathers produced different slot permutations, so slot-sliced
// ranking missed some elements and double-ranked others -> poisoned pool slots).
// Levels 3/4 get fully deterministic slots. Level boundaries are multiples of 64,
// so `level` is wave-uniform and the ballot aggregation below is safe.
__global__ __launch_bounds__(256) void gather_kernel(const uint4* __restrict__ dec,
                                                     const int* __restrict__ bcut,
                                                     unsigned long long* __restrict__ gbuf,
                                                     int* __restrict__ gcnt) {
  __shared__ int c[3];
  int img = blockIdx.x;
  int tid = threadIdx.x, lane = tid & 63;
  int b0 = bcut[img * 3 + 0], b1 = bcut[img * 3 + 1], b2 = bcut[img * 3 + 2];
  if (tid < 3) c[tid] = 0;
  __syncthreads();
  unsigned long long* gb = gbuf + (size_t)img * CAPTOT;

  for (int j = tid; j < NPOS; j += 256) {
    int level, hw;
    map_lvl(j, level, hw);
    unsigned nsb = ~dec[img * NPOS + j].x;
    unsigned long long key =
        ((unsigned long long)nsb << 32) | (unsigned)((level << 20) | hw);
    if (level >= 3) {                       // wave-uniform branch
      gb[SEG3 + ((level == 3) ? hw : 256 + hw)] = key;
    } else {
      int dg = (int)(nsb >> 19);
      bool sel = dg <= ((level == 0) ? b0 : (level == 1) ? b1 : b2);
      unsigned long long msk = __ballot(sel);
      if (msk) {
        int nsel = __popcll(msk);
        int bas = 0;
        if (lane == 0) bas = atomicAdd(&c[level], nsel);
        bas = __shfl(bas, 0, 64);
        if (sel) {
          int p = bas + __popcll(msk & ((1ULL << lane) - 1ULL));
          int cap   = (level == 0) ? CAP0 : (level == 1) ? CAP1 : CAP2;
          int sbase = (level == 0) ? 0    : (level == 1) ? SEG1 : SEG2;
          if (p < cap) gb[sbase + p] = key;
        }
      }
    }
  }
  __syncthreads();
  if (tid < 3) gcnt[img * 3 + tid] = c[tid];
}

// ---------------- kernel 3b: exact rank -> sorted pool ----------------
// Lemma (exactness): S_l = {y in level l : digit(y) <= B_l} is downward-closed with
// |S_l| >= 1000, so the level-l top-1000 are the 1000 smallest of S_l (threshold t_l =
// 1000th-smallest of S_l). For any x: if n_l(x) = #{S_l < x} < 1000 then x <= t_l and
// all excluded y > t_l >= x, so n_l is the exact within-level smaller-count; and
// min(n_l,1000) = #{selected level-l keys < x} in all cases. Levels 3/4 are complete.
// Hence pos(x) = sum_l min(n_l,1000) + n_34(x) is x's exact rank in the sorted
// 3320-pool, and a level<=2 key is selected iff its own-level n < 1000.
// All blocks load the SAME gbuf, so slot-sliced ownership covers each element once.
__global__ __launch_bounds__(256) void rank_kernel(const unsigned long long* __restrict__ gbuf,
                                                   const int* __restrict__ gcnt,
                                                   unsigned long long* __restrict__ pool) {
  __shared__ unsigned long long lk[CAPTOT];
  int img = blockIdx.x / RANK_BLOCKS, bl = blockIdx.x % RANK_BLOCKS;
  int tid = threadIdx.x;
  const unsigned long long* gb = gbuf + (size_t)img * CAPTOT;
  for (int i = tid; i < CAPTOT; i += 256) lk[i] = gb[i];
  __syncthreads();

  int c0 = min(gcnt[img * 3 + 0], CAP0);
  int c1 = min(gcnt[img * 3 + 1], CAP1);
  int c2 = min(gcnt[img * 3 + 2], CAP2);
  const int c34 = CAP34;

  int e = bl * 256 + tid;
  int seg, slot;
  if      (e < SEG1)   { seg = 0; slot = e; }
  else if (e < SEG2)   { seg = 1; slot = e - SEG1; }
  else if (e < SEG3)   { seg = 2; slot = e - SEG2; }
  else if (e < CAPTOT) { seg = 3; slot = e - SEG3; }
  else return;   // no barriers below
  bool valid = (seg == 0) ? (slot < c0) : (seg == 1) ? (slot < c1)
             : (seg == 2) ? (slot < c2) : (slot < c34);
  if (!valid) return;

  unsigned long long mk = lk[e];
  int n0 = 0, n1 = 0, n2 = 0, n34 = 0;
  for (int j = 0; j < c0; ++j)  n0  += (lk[j] < mk) ? 1 : 0;
  for (int j = 0; j < c1; ++j)  n1  += (lk[SEG1 + j] < mk) ? 1 : 0;
  for (int j = 0; j < c2; ++j)  n2  += (lk[SEG2 + j] < mk) ? 1 : 0;
  for (int j = 0; j < c34; ++j) n34 += (lk[SEG3 + j] < mk) ? 1 : 0;

  bool selected = (seg == 3) || (seg == 0 && n0 < 1000) ||
                  (seg == 1 && n1 < 1000) || (seg == 2 && n2 < 1000);
  if (selected) {
    int pos = min(n0, 1000) + min(n1, 1000) + min(n2, 1000) + n34;
    pool[img * POOLN + pos] = mk;
  }
}

// ---------------- kernel 4: per-image greedy NMS + output (bit-identical to R1) --
__global__ __launch_bounds__(64) void nms_kernel(const uint4* __restrict__ dec,
                                                 const unsigned long long* __restrict__ pool,
                                                 float* __restrict__ out) {
  __shared__ float          s_score[POOLN];
  __shared__ unsigned short s_cls[POOLN];
  __shared__ uint2          s_box[POOLN];
  int img = blockIdx.x;
  int lane = threadIdx.x;

  for (int r = lane; r < POOLN; r += 64) {
    unsigned long long key = pool[img * POOLN + r];
    unsigned low = (unsigned)key;
    int level = (low >> 20) & 7;
    int idx = low & 0xFFFFF;
    uint4 e = dec[img * NPOS + d_lvl_off[level] + idx];
    s_score[r] = __uint_as_float(e.x);
    s_cls[r]   = (unsigned short)e.y;
    s_box[r]   = make_uint2(e.z, e.w);
  }
  __syncthreads();

  float* out_s = out + img * MAXDET;
  float* out_c = out + BATCH * MAXDET + img * MAXDET;
  float* out_b = out + 2 * BATCH * MAXDET + img * MAXDET * 4;

  // kept boxes: slot s lives in lane (s & 63), reg (s >> 6)
  int kx1[2], ky1[2], kx2[2], ky2[2], kar[2];
  int k = 0;

  for (int i = 0; i < POOLN; ++i) {
    float sc = s_score[i];
    if (!(sc > 0.01f)) break;   // sorted desc: all remaining are invalid too
    uint2 bx = s_box[i];
    int x1 = bx.x & 0xFFFF, y1 = bx.x >> 16;
    int x2 = bx.y & 0xFFFF, y2 = bx.y >> 16;
    int area = (x2 - x1) * (y2 - y1);

    bool sup = false;
#pragma unroll
    for (int sidx = 0; sidx < 2; ++sidx) {
      int slot = (sidx << 6) | lane;
      if (slot < k) {
        int xx1 = max(x1, kx1[sidx]), yy1 = max(y1, ky1[sidx]);
        int xx2 = min(x2, kx2[sidx]), yy2 = min(y2, ky2[sidx]);
        int iw = max(xx2 - xx1, 0), ih = max(yy2 - yy1, 0);
        int inter = iw * ih;
        // all intermediates are exact small ints -> identical fp32 division to ref
        float iou = (float)inter / (float)(area + kar[sidx] - inter);
        sup = sup || (iou > 0.6f);
      }
    }
    if (!__any(sup)) {
      if ((k & 63) == lane) {
        int hi = k >> 6;
        kx1[hi] = x1; ky1[hi] = y1; kx2[hi] = x2; ky2[hi] = y2; kar[hi] = area;
      }
      if (lane == 0) {
        out_s[k] = sc;
        out_c[k] = (float)(int)s_cls[i];
        out_b[k * 4 + 0] = (float)x1;
        out_b[k * 4 + 1] = (float)y1;
        out_b[k * 4 + 2] = (float)x2;
        out_b[k * 4 + 3] = (float)y2;
      }
      ++k;
      if (k == MAXDET) break;
    }
  }

  for (int s = k + lane; s < MAXDET; s += 64) {
    out_s[s] = -1.0f;
    out_c[s] = -1.0f;
    out_b[s * 4 + 0] = -1.0f;
    out_b[s * 4 + 1] = -1.0f;
    out_b[s * 4 + 2] = -1.0f;
    out_b[s * 4 + 3] = -1.0f;
  }
}

// ---------------- launcher ----------------
extern "C" void kernel_launch(void* const* d_in, const int* in_sizes, int n_in,
                              void* d_out, int out_size, void* d_ws, size_t ws_size,
                              hipStream_t stream) {
  Ptrs args;
  for (int i = 0; i < 20; ++i) args.p[i] = (const float*)d_in[i];

  char* ws = (char*)d_ws;
  uint4* dec = (uint4*)ws;                              // 16*21824*16 = 5,586,944 B
  ws += (size_t)BATCH * NPOS * 16;
  unsigned long long* pool = (unsigned long long*)ws;   // 16*3320*8 = 424,960 B
  ws += (size_t)BATCH * POOLN * 8;
  unsigned long long* gbuf = (unsigned long long*)ws;   // 16*7872*8 = 1,007,616 B
  ws += (size_t)BATCH * CAPTOT * 8;
  int* bcut = (int*)ws;                                 // 192 B
  int* gcnt = bcut + BATCH * 3;                         // 192 B
  float* out = (float*)d_out;

  int total = BATCH * NPOS;
  decode_kernel<<<(total + 255) / 256, 256, 0, stream>>>(args, dec);
  hist_kernel<<<BATCH * 3, 256, 0, stream>>>(dec, bcut);
  gather_kernel<<<BATCH, 256, 0, stream>>>(dec, bcut, gbuf, gcnt);
  rank_kernel<<<BATCH * RANK_BLOCKS, 256, 0, stream>>>(gbuf, gcnt, pool);
  nms_kernel<<<BATCH, 64, 0, stream>>>(dec, pool, out);
}

// Round 5
// 386.254 us; speedup vs baseline: 1.2764x; 1.0221x over previous
//
#include <hip/hip_runtime.h>
#include <stdint.h>

// ---------------- problem constants ----------------
#define BATCH 16
#define NCLS 80
#define NPOS 21824            // 16384+4096+1024+256+64
#define POOLN 3320            // 1000+1000+1000+256+64
#define MAXDET 100

// superset segment capacities (all multiples of 8 for the unrolled rank loop)
#define CAP0 4096
#define CAP1 2432
#define CAP2 1024             // level 2 has only 1024 anchors total
#define CAP34 320             // levels 3+4 exactly (deterministic slots)
#define SEG1 (CAP0)                    // 4096
#define SEG2 (CAP0 + CAP1)             // 6528
#define SEG3 (CAP0 + CAP1 + CAP2)      // 7552
#define CAPTOT (SEG3 + CAP34)          // 7872
#define RANK_BLOCKS 31                 // 31*256 = 7936 >= CAPTOT

// decode tiling
#define DEC_BLOCK 128
#define DEC_STRIDE 81          // 81 = 17 mod 32, gcd(17,32)=1 -> conflict-free readback
#define BLOCKS_PER_IMG 171     // ceil(21824/128); all level boundaries are 128-aligned

#define GATHER_SPLIT 8
#define GATHER_CHUNK 2752      // multiple of 64 -> wave-uniform level; 7*2752+2560=21824

__device__ const int d_lvl_off[5] = {0, 16384, 20480, 21504, 21760};
__device__ const int d_lvl_hw[5]  = {16384, 4096, 1024, 256, 64};

struct Ptrs { const float* p[20]; };

__device__ __forceinline__ void map_lvl(int r, int& level, int& hw) {
  if      (r < 16384) { level = 0; hw = r; }
  else if (r < 20480) { level = 1; hw = r - 16384; }
  else if (r < 21504) { level = 2; hw = r - 20480; }
  else if (r < 21760) { level = 3; hw = r - 21504; }
  else                { level = 4; hw = r - 21760; }
}

// key = (~score_bits)<<32 | (level<<20) | hw; ascending == (score desc, level asc, idx asc).
// Unique per image; real keys always have top bit set and level<8, so ~0ULL is a safe
// strictly-greater sentinel (never counted by `< mk`).

// ---------------- kernel 1: decode (LDS-staged coalesced cls reads) ----------------
// Same math as the R1/R4 decode (absmax 0.0); only the cls access pattern changed:
// coalesced float4 tile load -> LDS (stride-81 rows) -> in-order argmax scan.
__global__ __launch_bounds__(DEC_BLOCK) void decode_kernel(Ptrs args, uint4* __restrict__ dec) {
  __shared__ float scl[DEC_BLOCK * DEC_STRIDE];   // 41,472 B
  int b  = blockIdx.x / BLOCKS_PER_IMG;
  int bb = blockIdx.x % BLOCKS_PER_IMG;
  int flat0 = bb * DEC_BLOCK;
  int t = threadIdx.x;
  int level, hw0;
  map_lvl(flat0, level, hw0);                      // whole block lies in one level
  int HW = d_lvl_hw[level];
  int n_anch = min(DEC_BLOCK, NPOS - flat0);       // 128, or 64 for the last block

  const float* cls = args.p[level * 4 + 0];
  const float* reg = args.p[level * 4 + 1];
  const float* ctr = args.p[level * 4 + 2];
  const float* pos = args.p[level * 4 + 3];
  long abase = (long)b * HW + hw0;

  const float4* g4 = (const float4*)(cls + abase * NCLS);   // 320B-aligned
  int nf4 = n_anch * (NCLS / 4);
  for (int i = t; i < nf4; i += DEC_BLOCK) {
    float4 v = g4[i];
    int a = i / 20, q = (i % 20) * 4;
    float* row = &scl[a * DEC_STRIDE + q];
    row[0] = v.x; row[1] = v.y; row[2] = v.z; row[3] = v.w;
  }
  __syncthreads();
  if (t >= n_anch) return;

  // argmax over 80 logits, first occurrence (sigmoid monotone). 4 chains of 20,
  // combined in segment order with strict '>' -> earliest global index on ties.
  const float* row = &scl[t * DEC_STRIDE];
  float mm0 = -1e30f, mm1 = -1e30f, mm2 = -1e30f, mm3 = -1e30f;
  int aa0 = 0, aa1 = 0, aa2 = 0, aa3 = 0;
#pragma unroll
  for (int c = 0; c < 20; ++c) {
    float v0 = row[c], v1 = row[20 + c], v2 = row[40 + c], v3 = row[60 + c];
    if (v0 > mm0) { mm0 = v0; aa0 = c; }
    if (v1 > mm1) { mm1 = v1; aa1 = 20 + c; }
    if (v2 > mm2) { mm2 = v2; aa2 = 40 + c; }
    if (v3 > mm3) { mm3 = v3; aa3 = 60 + c; }
  }
  float m = mm0; int am = aa0;
  if (mm1 > m) { m = mm1; am = aa1; }
  if (mm2 > m) { m = mm2; am = aa2; }
  if (mm3 > m) { m = mm3; am = aa3; }

  long base = abase + t;
  float4 rg = *(const float4*)(reg + base * 4);
  float  ct = ctr[base];
  float  px = pos[base * 2 + 0], py = pos[base * 2 + 1];

  float e0 = expf(rg.x), e1 = expf(rg.y), e2 = expf(rg.z), e3 = expf(rg.w);
  int x1 = (int)(px - e0);   // C truncation == .astype(int32)
  int y1 = (int)(py - e1);
  int x2 = (int)(px + e2);
  int y2 = (int)(py + e3);
  x1 = max(x1, 0); y1 = max(y1, 0);
  x2 = min(x2, 1023); y2 = min(y2, 1023);

  float sigm = 1.0f / (1.0f + expf(-m));
  float sigc = 1.0f / (1.0f + expf(-ct));
  float score = sqrtf(sigm * sigc);

  uint4 e;
  e.x = __float_as_uint(score);
  e.y = (unsigned)am;
  e.z = (unsigned)(x1 & 0xFFFF) | ((unsigned)y1 << 16);
  e.w = (unsigned)(x2 & 0xFFFF) | ((unsigned)y2 << 16);
  dec[b * NPOS + flat0 + t] = e;
}

// ---------------- kernel 2: per-(img,level) coarse digit cutoff ----------------
// digit = (~score_bits) >> 19 is a 13-bit PREFIX of the sort key, so {digit <= B}
// is downward-closed in key order. Pick smallest B with cum >= 1000.
// Also zeroes gcnt (poisoned 0xAA) for the parallel gather that follows.
__global__ __launch_bounds__(256) void hist_kernel(const uint4* __restrict__ dec,
                                                   int* __restrict__ bcut,
                                                   int* __restrict__ gcnt) {
  __shared__ unsigned hist[8192];
  __shared__ unsigned part[256];
  int img = blockIdx.x / 3, level = blockIdx.x % 3;
  int N = d_lvl_hw[level];
  const uint4* base = dec + img * NPOS + d_lvl_off[level];
  int tid = threadIdx.x;

  if (tid == 0) gcnt[img * 3 + level] = 0;
  for (int i = tid; i < 8192; i += 256) hist[i] = 0;
  __syncthreads();
  for (int i = tid; i < N; i += 256)
    atomicAdd(&hist[(~base[i].x) >> 19], 1u);
  __syncthreads();
  unsigned s = 0;
  for (int b = 32 * tid; b < 32 * tid + 32; ++b) s += hist[b];
  part[tid] = s;
  __syncthreads();
  if (tid == 0) {
    unsigned cum = 0; int B = 8191;
    for (int t = 0; t < 256; ++t) {
      if (cum + part[t] >= 1000u) {
        for (int b = 32 * t; b < 32 * t + 32; ++b) {
          cum += hist[b];
          if (cum >= 1000u) { B = b; break; }
        }
        break;
      }
      cum += part[t];
    }
    bcut[img * 3 + level] = B;
  }
}

// ---------------- kernel 3a: single-LAYOUT gather of supersets -> global ------
// 8 blocks per image, sharing ONE global atomic counter per (img,level): every
// element is placed exactly once into one consistent gbuf layout (the R2/R3 bug
// was per-block redundant gathers with per-block layouts). Chunks are multiples
// of 64 so `level` is wave-uniform for the ballot/leader logic.
__global__ __launch_bounds__(256) void gather_kernel(const uint4* __restrict__ dec,
                                                     const int* __restrict__ bcut,
                                                     unsigned long long* __restrict__ gbuf,
                                                     int* __restrict__ gcnt) {
  int img = blockIdx.x / GATHER_SPLIT, bb = blockIdx.x % GATHER_SPLIT;
  int tid = threadIdx.x, lane = tid & 63;
  int start = bb * GATHER_CHUNK, end = min(start + GATHER_CHUNK, NPOS);
  int b0 = bcut[img * 3 + 0], b1 = bcut[img * 3 + 1], b2 = bcut[img * 3 + 2];
  unsigned long long* gb = gbuf + (size_t)img * CAPTOT;

  for (int j = start + tid; j < end; j += 256) {
    int level, hw;
    map_lvl(j, level, hw);
    unsigned nsb = ~dec[img * NPOS + j].x;
    unsigned long long key =
        ((unsigned long long)nsb << 32) | (unsigned)((level << 20) | hw);
    if (level >= 3) {                       // wave-uniform branch
      gb[SEG3 + ((level == 3) ? hw : 256 + hw)] = key;
    } else {
      int dg = (int)(nsb >> 19);
      bool sel = dg <= ((level == 0) ? b0 : (level == 1) ? b1 : b2);
      unsigned long long msk = __ballot(sel);
      if (msk) {
        int nsel = __popcll(msk);
        int bas = 0;
        if (lane == 0) bas = atomicAdd(&gcnt[img * 3 + level], nsel);
        bas = __shfl(bas, 0, 64);
        if (sel) {
          int p = bas + __popcll(msk & ((1ULL << lane) - 1ULL));
          int cap   = (level == 0) ? CAP0 : (level == 1) ? CAP1 : CAP2;
          int sbase = (level == 0) ? 0    : (level == 1) ? SEG1 : SEG2;
          if (p < cap) gb[sbase + p] = key;
        }
      }
    }
  }
}

// ---------------- kernel 3b: exact rank -> sorted pool ----------------
// Exactness lemma unchanged from R4 (which passed with absmax 0.0):
// pos(x) = sum_l min(n_l,1000) + n_34(x); level<=2 selected iff own-level n < 1000.
// NEW: segments padded to multiples of 8 with ~0ULL sentinels (> any real key, never
// counted) + 8x-unrolled compare loops -> 8 outstanding broadcast LDS reads hide the
// ~120-cycle ds_read latency that made R4's rank 74 us at 19% VALUBusy.
__global__ __launch_bounds__(256) void rank_kernel(const unsigned long long* __restrict__ gbuf,
                                                   const int* __restrict__ gcnt,
                                                   unsigned long long* __restrict__ pool) {
  __shared__ __align__(16) unsigned long long lk[CAPTOT];
  int img = blockIdx.x / RANK_BLOCKS, bl = blockIdx.x % RANK_BLOCKS;
  int tid = threadIdx.x;
  const unsigned long long* gb = gbuf + (size_t)img * CAPTOT;
  for (int i = tid; i < CAPTOT / 2; i += 256)
    ((ulonglong2*)lk)[i] = ((const ulonglong2*)gb)[i];

  int c0 = min(gcnt[img * 3 + 0], CAP0);
  int c1 = min(gcnt[img * 3 + 1], CAP1);
  int c2 = min(gcnt[img * 3 + 2], CAP2);
  const int c34 = CAP34;                       // multiple of 8 already
  int c0p = (c0 + 7) & ~7;                     // caps are multiples of 8 -> c*p <= CAP*
  int c1p = (c1 + 7) & ~7;
  int c2p = (c2 + 7) & ~7;
  __syncthreads();                             // loads done before sentinel writes
  if (tid < 8)       { int j = c0 + tid;        if (j < c0p) lk[j] = ~0ULL; }
  else if (tid < 16) { int j = c1 + (tid - 8);  if (j < c1p) lk[SEG1 + j] = ~0ULL; }
  else if (tid < 24) { int j = c2 + (tid - 16); if (j < c2p) lk[SEG2 + j] = ~0ULL; }
  __syncthreads();

  int e = bl * 256 + tid;
  int seg, slot;
  if      (e < SEG1)   { seg = 0; slot = e; }
  else if (e < SEG2)   { seg = 1; slot = e - SEG1; }
  else if (e < SEG3)   { seg = 2; slot = e - SEG2; }
  else if (e < CAPTOT) { seg = 3; slot = e - SEG3; }
  else return;   // no barriers below
  bool valid = (seg == 0) ? (slot < c0) : (seg == 1) ? (slot < c1)
             : (seg == 2) ? (slot < c2) : (slot < c34);
  if (!valid) return;

  unsigned long long mk = lk[e];
  int n0 = 0, n1 = 0, n2 = 0, n34 = 0;
#define CNT8(acc, arr, off, lim)                                                   \
  for (int j = 0; j < (lim); j += 8) {                                             \
    unsigned long long a0 = (arr)[(off) + j + 0], a1 = (arr)[(off) + j + 1];       \
    unsigned long long a2 = (arr)[(off) + j + 2], a3 = (arr)[(off) + j + 3];       \
    unsigned long long a4 = (arr)[(off) + j + 4], a5 = (arr)[(off) + j + 5];       \
    unsigned long long a6 = (arr)[(off) + j + 6], a7 = (arr)[(off) + j + 7];       \
    acc += (int)(a0 < mk) + (int)(a1 < mk) + (int)(a2 < mk) + (int)(a3 < mk) +     \
           (int)(a4 < mk) + (int)(a5 < mk) + (int)(a6 < mk) + (int)(a7 < mk);      \
  }
  CNT8(n0,  lk, 0,    c0p)
  CNT8(n1,  lk, SEG1, c1p)
  CNT8(n2,  lk, SEG2, c2p)
  CNT8(n34, lk, SEG3, c34)
#undef CNT8

  bool selected = (seg == 3) || (seg == 0 && n0 < 1000) ||
                  (seg == 1 && n1 < 1000) || (seg == 2 && n2 < 1000);
  if (selected) {
    int pos = min(n0, 1000) + min(n1, 1000) + min(n2, 1000) + n34;
    pool[img * POOLN + pos] = mk;
  }
}

// ---------------- kernel 4: per-image greedy NMS + output (bit-identical, proven) --
__global__ __launch_bounds__(64) void nms_kernel(const uint4* __restrict__ dec,
                                                 const unsigned long long* __restrict__ pool,
                                                 float* __restrict__ out) {
  __shared__ float          s_score[POOLN];
  __shared__ unsigned short s_cls[POOLN];
  __shared__ uint2          s_box[POOLN];
  int img = blockIdx.x;
  int lane = threadIdx.x;

  for (int r = lane; r < POOLN; r += 64) {
    unsigned long long key = pool[img * POOLN + r];
    unsigned low = (unsigned)key;
    int level = (low >> 20) & 7;
    int idx = low & 0xFFFFF;
    uint4 e = dec[img * NPOS + d_lvl_off[level] + idx];
    s_score[r] = __uint_as_float(e.x);
    s_cls[r]   = (unsigned short)e.y;
    s_box[r]   = make_uint2(e.z, e.w);
  }
  __syncthreads();

  float* out_s = out + img * MAXDET;
  float* out_c = out + BATCH * MAXDET + img * MAXDET;
  float* out_b = out + 2 * BATCH * MAXDET + img * MAXDET * 4;

  // kept boxes: slot s lives in lane (s & 63), reg (s >> 6)
  int kx1[2], ky1[2], kx2[2], ky2[2], kar[2];
  int k = 0;

  for (int i = 0; i < POOLN; ++i) {
    float sc = s_score[i];
    if (!(sc > 0.01f)) break;   // sorted desc: all remaining are invalid too
    uint2 bx = s_box[i];
    int x1 = bx.x & 0xFFFF, y1 = bx.x >> 16;
    int x2 = bx.y & 0xFFFF, y2 = bx.y >> 16;
    int area = (x2 - x1) * (y2 - y1);

    bool sup = false;
#pragma unroll
    for (int sidx = 0; sidx < 2; ++sidx) {
      int slot = (sidx << 6) | lane;
      if (slot < k) {
        int xx1 = max(x1, kx1[sidx]), yy1 = max(y1, ky1[sidx]);
        int xx2 = min(x2, kx2[sidx]), yy2 = min(y2, ky2[sidx]);
        int iw = max(xx2 - xx1, 0), ih = max(yy2 - yy1, 0);
        int inter = iw * ih;
        // all intermediates are exact small ints -> identical fp32 division to ref
        float iou = (float)inter / (float)(area + kar[sidx] - inter);
        sup = sup || (iou > 0.6f);
      }
    }
    if (!__any(sup)) {
      if ((k & 63) == lane) {
        int hi = k >> 6;
        kx1[hi] = x1; ky1[hi] = y1; kx2[hi] = x2; ky2[hi] = y2; kar[hi] = area;
      }
      if (lane == 0) {
        out_s[k] = sc;
        out_c[k] = (float)(int)s_cls[i];
        out_b[k * 4 + 0] = (float)x1;
        out_b[k * 4 + 1] = (float)y1;
        out_b[k * 4 + 2] = (float)x2;
        out_b[k * 4 + 3] = (float)y2;
      }
      ++k;
      if (k == MAXDET) break;
    }
  }

  for (int s = k + lane; s < MAXDET; s += 64) {
    out_s[s] = -1.0f;
    out_c[s] = -1.0f;
    out_b[s * 4 + 0] = -1.0f;
    out_b[s * 4 + 1] = -1.0f;
    out_b[s * 4 + 2] = -1.0f;
    out_b[s * 4 + 3] = -1.0f;
  }
}

// ---------------- launcher ----------------
extern "C" void kernel_launch(void* const* d_in, const int* in_sizes, int n_in,
                              void* d_out, int out_size, void* d_ws, size_t ws_size,
                              hipStream_t stream) {
  Ptrs args;
  for (int i = 0; i < 20; ++i) args.p[i] = (const float*)d_in[i];

  char* ws = (char*)d_ws;
  uint4* dec = (uint4*)ws;                              // 16*21824*16 = 5,586,944 B
  ws += (size_t)BATCH * NPOS * 16;
  unsigned long long* pool = (unsigned long long*)ws;   // 16*3320*8 = 424,960 B
  ws += (size_t)BATCH * POOLN * 8;
  unsigned long long* gbuf = (unsigned long long*)ws;   // 16*7872*8 = 1,007,616 B (16B-aligned)
  ws += (size_t)BATCH * CAPTOT * 8;
  int* bcut = (int*)ws;                                 // 192 B
  int* gcnt = bcut + BATCH * 3;                         // 192 B
  float* out = (float*)d_out;

  decode_kernel<<<BATCH * BLOCKS_PER_IMG, DEC_BLOCK, 0, stream>>>(args, dec);
  hist_kernel<<<BATCH * 3, 256, 0, stream>>>(dec, bcut, gcnt);
  gather_kernel<<<BATCH * GATHER_SPLIT, 256, 0, stream>>>(dec, bcut, gbuf, gcnt);
  rank_kernel<<<BATCH * RANK_BLOCKS, 256, 0, stream>>>(gbuf, gcnt, pool);
  nms_kernel<<<BATCH, 64, 0, stream>>>(dec, pool, out);
}